// Round 12
// baseline (123.554 us; speedup 1.0000x reference)
//
#include <hip/hip_runtime.h>
#include <math.h>

// B=65536, D=8, H=2 (hd=4), S=15 tokens, A=20 outputs.
// R12 = R10 (best measured) + persistent x2 blocks: grid 2048, each block does
// 2 consecutive 16-element groups. Table copy+barrier amortized 2x; both
// iterations' index loads issued up-front (HBM latency of iter-2 hidden under
// iter-1 compute). Per-iteration math/barriers identical to R10 (absmax
// 0.03125-proven). kvb rows are wave-private -> no extra barrier across iters.
#define EPB 16
#define ITERS 2
#define BTOT 65536
#define C_SCALE 0.72134752044f  // 0.5 * log2(e)

typedef _Float16 h2 __attribute__((ext_vector_type(2)));
typedef __fp16 fp16v2 __attribute__((ext_vector_type(2)));

// d_ws h2 layout offsets (h2 = 4B, same index granularity as float)
#define WQKV1 0     // 96: [c2=0..11][j pairs]; q rows (2c,2c+1)*C_SCALE, k rows seq
#define BQKV1 96    // 12
#define WO0   108   // 32: cols reordered (p, p+4) for interleaved-o input
#define BO0   140   // 4
#define WL0   144   // 32: natural
#define BL0   176   // 4
#define WO1   180   // 32: cols reordered
#define BO1   212   // 4
#define WL1   216   // 32: natural
#define BL1   248   // 4
#define WV1P  256   // 32: [r=0..7][p=0..3]; rows permuted v0,v4,v1,v5,v2,v6,v3,v7
#define BV1F  288   // 8 f32 biases (permuted)
#define XT    304   // 128: x rows, seq pairs
#define VT    432   // 128: layer-0 v rows, head-interleaved pairs (stride 4)
#define ET    560   // 1056: e[qi*33+ki] = (e_h0, e_h1) f16
#define WOUTF 1616  // 160 f32: Wout/15, [a][j]
#define BOUTF 1776  // 20 f32: bout
#define TBL0  304
#define TBLV4 328
#define XTO 0
#define VTO 128
#define ETO 256

__device__ __forceinline__ float exp2_fast(float x) { return __builtin_amdgcn_exp2f(x); }
__device__ __forceinline__ float rcp_fast(float x)  { return __builtin_amdgcn_rcpf(x); }
__device__ __forceinline__ h2 pkrtz(float a, float b) {
  fp16v2 r = __builtin_amdgcn_cvt_pkrtz(a, b);
  return __builtin_bit_cast(h2, r);
}
__device__ __forceinline__ float fdot2f(h2 a, h2 b, float c) {
#if defined(__has_builtin) && __has_builtin(__builtin_amdgcn_fdot2)
  return __builtin_amdgcn_fdot2(a, b, c, false);
#else
  return (float)a.x * (float)b.x + (float)a.y * (float)b.y + c;
#endif
}

union F4H2 { float4 f; h2 h[4]; };
union H2I { h2 h; int i; };

__device__ __forceinline__ void mm8_h2(const h2* __restrict__ wp, int woff, int boff,
                                       const h2 in2[4], h2 out2[4])
{
#pragma unroll
  for (int c2 = 0; c2 < 4; ++c2) {
    h2 acc = wp[boff + c2];
#pragma unroll
    for (int p = 0; p < 4; ++p) {
      acc += (h2)(in2[p].x) * wp[woff + c2 * 8 + 2 * p];
      acc += (h2)(in2[p].y) * wp[woff + c2 * 8 + 2 * p + 1];
    }
    out2[c2] = acc;
  }
}

__global__ void BetterBot_setup(
    const float* __restrict__ emb_dice, const float* __restrict__ emb_star,
    const float* __restrict__ emb_btns,
    const float* __restrict__ Wout, const float* __restrict__ bout,
    const float* __restrict__ Wqkv0, const float* __restrict__ bqkv0,
    const float* __restrict__ Wqkv1, const float* __restrict__ bqkv1,
    const float* __restrict__ Wo0, const float* __restrict__ bo0,
    const float* __restrict__ Wl0, const float* __restrict__ bl0,
    const float* __restrict__ Wo1, const float* __restrict__ bo1,
    const float* __restrict__ Wl1, const float* __restrict__ bl1,
    h2* __restrict__ ws)
{
  __shared__ float qs[32][8], ks[32][8], vs[32][8];
  const int tid = threadIdx.x;
  float* wsf = (float*)ws;

  if (tid < 96) {
    const int c2 = tid >> 3, j = tid & 7;
    int ra, rb; float s = 1.0f;
    if (c2 < 4)      { ra = 2 * c2; rb = ra + 1; s = C_SCALE; }
    else if (c2 < 8) { ra = 8 + 2 * (c2 - 4); rb = ra + 1; }
    else             { ra = 16 + (c2 - 8); rb = ra + 4; }
    ws[tid] = pkrtz(Wqkv1[ra * 8 + j] * s, Wqkv1[rb * 8 + j] * s);
  } else if (tid < 108) {
    const int c2 = tid - 96;
    int ra, rb; float s = 1.0f;
    if (c2 < 4)      { ra = 2 * c2; rb = ra + 1; s = C_SCALE; }
    else if (c2 < 8) { ra = 8 + 2 * (c2 - 4); rb = ra + 1; }
    else             { ra = 16 + (c2 - 8); rb = ra + 4; }
    ws[tid] = pkrtz(bqkv1[ra] * s, bqkv1[rb] * s);
  } else if (tid < 140) {
    const int k = tid - 108, c2 = k >> 3, j = k & 7, p = j >> 1;
    const int col = (j & 1) ? (p + 4) : p;
    ws[tid] = pkrtz(Wo0[(2 * c2) * 8 + col], Wo0[(2 * c2 + 1) * 8 + col]);
  } else if (tid < 144) {
    const int c2 = tid - 140;
    ws[tid] = pkrtz(bo0[2 * c2], bo0[2 * c2 + 1]);
  } else if (tid < 176) {
    const int k = tid - 144, c2 = k >> 3, j = k & 7;
    ws[tid] = pkrtz(Wl0[(2 * c2) * 8 + j], Wl0[(2 * c2 + 1) * 8 + j]);
  } else if (tid < 180) {
    const int c2 = tid - 176;
    ws[tid] = pkrtz(bl0[2 * c2], bl0[2 * c2 + 1]);
  } else if (tid < 212) {
    const int k = tid - 180, c2 = k >> 3, j = k & 7, p = j >> 1;
    const int col = (j & 1) ? (p + 4) : p;
    ws[tid] = pkrtz(Wo1[(2 * c2) * 8 + col], Wo1[(2 * c2 + 1) * 8 + col]);
  } else if (tid < 216) {
    const int c2 = tid - 212;
    ws[tid] = pkrtz(bo1[2 * c2], bo1[2 * c2 + 1]);
  } else if (tid < 248) {
    const int k = tid - 216, c2 = k >> 3, j = k & 7;
    ws[tid] = pkrtz(Wl1[(2 * c2) * 8 + j], Wl1[(2 * c2 + 1) * 8 + j]);
  } else if (tid < 252) {
    const int c2 = tid - 248;
    ws[tid] = pkrtz(bl1[2 * c2], bl1[2 * c2 + 1]);
  }
  if (tid < 32) {
    const int r = tid >> 2, p = tid & 3;
    const int row = 16 + (r >> 1) + (r & 1) * 4;   // perm: v0,v4,v1,v5,v2,v6,v3,v7
    ws[WV1P + tid] = pkrtz(Wqkv1[row * 8 + 2 * p], Wqkv1[row * 8 + 2 * p + 1]);
  } else if (tid < 40) {
    const int r = tid - 32;
    const int row = 16 + (r >> 1) + (r & 1) * 4;
    wsf[BV1F + r] = bqkv1[row];
  }
  if (tid < 160)      wsf[WOUTF + tid] = Wout[tid] * (1.0f / 15.0f);
  else if (tid < 180) wsf[BOUTF + tid - 160] = bout[tid - 160];

  {
    const int c = tid >> 3, l8 = tid & 7;
    const float* er;
    if (c < 15)      er = emb_dice + 8 * c;
    else if (c < 30) er = emb_star + 8 * (c - 15);
    else             er = emb_btns + 8 * (c - 30);
    const float4 r0 = ((const float4*)er)[0];
    const float4 r1 = ((const float4*)er)[1];
    float r[8] = {r0.x, r0.y, r0.z, r0.w, r1.x, r1.y, r1.z, r1.w};
    if (l8 < 4) ws[XT + c * 4 + l8] = pkrtz(r[2 * l8], r[2 * l8 + 1]);
    float aq = bqkv0[l8], ak = bqkv0[8 + l8], av = bqkv0[16 + l8];
#pragma unroll
    for (int j = 0; j < 8; ++j) {
      aq = fmaf(r[j], Wqkv0[l8 * 8 + j], aq);
      ak = fmaf(r[j], Wqkv0[(8 + l8) * 8 + j], ak);
      av = fmaf(r[j], Wqkv0[(16 + l8) * 8 + j], av);
    }
    qs[c][l8] = aq * C_SCALE;
    ks[c][l8] = ak;
    vs[c][l8] = av;
  }
  __syncthreads();

  {
    const int qi = tid >> 3, l8 = tid & 7;
    float q[8];
#pragma unroll
    for (int j = 0; j < 8; ++j) q[j] = qs[qi][j];
#pragma unroll
    for (int jj = 0; jj < 4; ++jj) {
      const int ki = l8 + 8 * jj;
      float s0 = q[0] * ks[ki][0];
      s0 = fmaf(q[1], ks[ki][1], s0); s0 = fmaf(q[2], ks[ki][2], s0); s0 = fmaf(q[3], ks[ki][3], s0);
      float s1 = q[4] * ks[ki][4];
      s1 = fmaf(q[5], ks[ki][5], s1); s1 = fmaf(q[6], ks[ki][6], s1); s1 = fmaf(q[7], ks[ki][7], s1);
      ws[ET + qi * 33 + ki] = pkrtz(exp2_fast(s0), exp2_fast(s1));
    }
  }
  if (tid < 32) {
#pragma unroll
    for (int p = 0; p < 4; ++p) ws[VT + tid * 4 + p] = pkrtz(vs[tid][p], vs[tid][p + 4]);
  }
}

__global__ __launch_bounds__(256, 8) void BetterBot_44169443672375_kernel(
    const int* __restrict__ dice_type, const int* __restrict__ dice_star,
    const int* __restrict__ summon_lvl,
    const h2* __restrict__ wp,
    float* __restrict__ out)
{
  __shared__ __align__(16) h2 tbl[1312];        // [xT 128 | vT 128 | eT 1056]
  __shared__ __align__(16) h2 kvb[EPB][17][8];  // token: [k 4xh2 | v 4xh2]; wave-private rows

  const int tid = threadIdx.x;
  const int e = tid >> 4;       // element in block
  const int t = tid & 15;       // token (15 = pad lane)
  const float* wsf = (const float*)wp;

  // ---- table copy + BOTH iterations' index loads issued up-front ----
  {
    float4* d = (float4*)tbl;
    const float4* s = (const float4*)(wp + TBL0);
    d[tid] = s[tid];
    if (tid < TBLV4 - 256) d[256 + tid] = s[256 + tid];
  }
  int myc[ITERS];
#pragma unroll
  for (int it = 0; it < ITERS; ++it) {
    const int ge = (blockIdx.x * ITERS + it) * EPB + e;
    int c = 0;
    if (t < 15) {
      if (t < 5)       c = dice_type[ge * 5 + t];
      else if (t < 10) c = 15 + dice_star[ge * 5 + (t - 5)];
      else             c = 30 + summon_lvl[ge * 5 + (t - 10)];
    }
    myc[it] = c;
  }
  int W[ITERS][4];
#pragma unroll
  for (int it = 0; it < ITERS; ++it) {
    int wv = myc[it] << (8 * (t & 3));
    wv |= __shfl_xor(wv, 1);
    wv |= __shfl_xor(wv, 2);
    const int gb = (tid & 63) & 48;
#pragma unroll
    for (int k2 = 0; k2 < 4; ++k2) W[it][k2] = __shfl(wv, gb + 4 * k2);
  }
  __syncthreads();   // tbl ready (the only cross-wave dependency)

#pragma unroll
  for (int it = 0; it < ITERS; ++it) {
    const int ge = (blockIdx.x * ITERS + it) * EPB + e;
    const int mc = myc[it];

    // ---- layer 0 (table-driven pk) + layer-1 qkv ----
    h2 x2[4] = {(h2)(_Float16)0.f, (h2)(_Float16)0.f, (h2)(_Float16)0.f, (h2)(_Float16)0.f};
    h2 q2[4];
    if (t < 15) {
      F4H2 xx; xx.f = *(const float4*)(&tbl[XTO + mc * 4]);
#pragma unroll
      for (int p = 0; p < 4; ++p) x2[p] = xx.h[p];

      h2 o2[4] = {(h2)(_Float16)0.f, (h2)(_Float16)0.f, (h2)(_Float16)0.f, (h2)(_Float16)0.f};
      h2 os2 = (h2)(_Float16)0.f;          // pk sums; table e bounded (R9-proven)
      const h2* myE = tbl + ETO + mc * 33;
#pragma unroll
      for (int u = 0; u < 15; ++u) {
        const int uc = (W[it][u >> 2] >> (8 * (u & 3))) & 0xff;
        const h2 ee2 = myE[uc];
        F4H2 vv; vv.f = *(const float4*)(&tbl[VTO + uc * 4]);
        os2 += ee2;
        o2[0] += ee2 * vv.h[0];
        o2[1] += ee2 * vv.h[1];
        o2[2] += ee2 * vv.h[2];
        o2[3] += ee2 * vv.h[3];
      }
      const h2 rp2 = pkrtz(rcp_fast((float)os2.x), rcp_fast((float)os2.y));
#pragma unroll
      for (int p = 0; p < 4; ++p) o2[p] *= rp2;

      h2 y2[4], xn2[4], hh2[4];
      mm8_h2(wp, WO0, BO0, o2, y2);
#pragma unroll
      for (int p = 0; p < 4; ++p) xn2[p] = x2[p] + y2[p];
      mm8_h2(wp, WL0, BL0, xn2, hh2);
      const h2 z2 = (h2)(_Float16)0.f;
#pragma unroll
      for (int p = 0; p < 4; ++p) x2[p] = xn2[p] + __builtin_elementwise_max(hh2[p], z2);

      // layer-1 q,k (pk-f16) + v (f32 fdot2, permuted rows)
      h2 qkv2[8];
#pragma unroll
      for (int c2 = 0; c2 < 8; ++c2) {
        h2 acc = wp[BQKV1 + c2];
#pragma unroll
        for (int p = 0; p < 4; ++p) {
          acc += (h2)(x2[p].x) * wp[WQKV1 + c2 * 8 + 2 * p];
          acc += (h2)(x2[p].y) * wp[WQKV1 + c2 * 8 + 2 * p + 1];
        }
        qkv2[c2] = acc;
      }
#pragma unroll
      for (int p = 0; p < 4; ++p) q2[p] = qkv2[p];
      float vv[8];
#pragma unroll
      for (int r = 0; r < 8; ++r) {
        float acc = wsf[BV1F + r];
#pragma unroll
        for (int p = 0; p < 4; ++p) acc = fdot2f(x2[p], wp[WV1P + r * 4 + p], acc);
        vv[r] = acc;
      }
      F4H2 kw;
#pragma unroll
      for (int p = 0; p < 4; ++p) kw.h[p] = qkv2[4 + p];
      *(float4*)(&kvb[e][t][0]) = kw.f;
      F4H2 vw;                              // v as f16 pairs (bounded; e stays f32)
      vw.h[0] = pkrtz(vv[0], vv[1]);
      vw.h[1] = pkrtz(vv[2], vv[3]);
      vw.h[2] = pkrtz(vv[4], vv[5]);
      vw.h[3] = pkrtz(vv[6], vv[7]);
      *(float4*)(&kvb[e][t][4]) = vw.f;
    }
    __syncthreads();   // R10 semantics: kvb write -> read

    // ---- layer 1: fdot2 f16 scores, f32 exp/sums/PV (fma_mix on f16 v) ----
    if (t < 15) {
      float o[8] = {0.f, 0.f, 0.f, 0.f, 0.f, 0.f, 0.f, 0.f};  // permuted order
      float sum0 = 0.f, sum1 = 0.f;
#pragma unroll
      for (int u = 0; u < 15; ++u) {
        F4H2 kk; kk.f = *(const float4*)(&kvb[e][u][0]);
        F4H2 vh; vh.f = *(const float4*)(&kvb[e][u][4]);
        const float s0 = fdot2f(q2[0], kk.h[0], fdot2f(q2[1], kk.h[1], 0.f));
        const float s1 = fdot2f(q2[2], kk.h[2], fdot2f(q2[3], kk.h[3], 0.f));
        const float e0 = exp2_fast(s0);
        const float e1 = exp2_fast(s1);
        sum0 += e0; sum1 += e1;
        o[0] = fmaf(e0, (float)vh.h[0].x, o[0]);
        o[1] = fmaf(e1, (float)vh.h[0].y, o[1]);
        o[2] = fmaf(e0, (float)vh.h[1].x, o[2]);
        o[3] = fmaf(e1, (float)vh.h[1].y, o[3]);
        o[4] = fmaf(e0, (float)vh.h[2].x, o[4]);
        o[5] = fmaf(e1, (float)vh.h[2].y, o[5]);
        o[6] = fmaf(e0, (float)vh.h[3].x, o[6]);
        o[7] = fmaf(e1, (float)vh.h[3].y, o[7]);
      }
      const float r0 = rcp_fast(sum0), r1 = rcp_fast(sum1);
      h2 po2[4];
#pragma unroll
      for (int i = 0; i < 4; ++i) po2[i] = pkrtz(o[2 * i] * r0, o[2 * i + 1] * r1);

      h2 y2[4], xn2[4], hh2[4];
      mm8_h2(wp, WO1, BO1, po2, y2);
#pragma unroll
      for (int p = 0; p < 4; ++p) xn2[p] = x2[p] + y2[p];
      mm8_h2(wp, WL1, BL1, xn2, hh2);
      const h2 z2 = (h2)(_Float16)0.f;
#pragma unroll
      for (int p = 0; p < 4; ++p) x2[p] = xn2[p] + __builtin_elementwise_max(hh2[p], z2);
    } else {
#pragma unroll
      for (int p = 0; p < 4; ++p) x2[p] = (h2)(_Float16)0.f;  // pad lane contributes 0
    }

    // ---- epilogue: token-sum via h2 butterfly; 1/15 pre-folded into Wout' ----
    h2 p2[4];
#pragma unroll
    for (int p = 0; p < 4; ++p) p2[p] = x2[p];
#pragma unroll
    for (int m = 1; m <= 8; m <<= 1) {
#pragma unroll
      for (int p = 0; p < 4; ++p) {
        H2I a; a.h = p2[p];
        H2I b; b.i = __shfl_xor(a.i, m);
        p2[p] += b.h;
      }
    }
    float sx[8];
#pragma unroll
    for (int i = 0; i < 4; ++i) { sx[2 * i] = (float)p2[i].x; sx[2 * i + 1] = (float)p2[i].y; }

    const int obase = ge * 20;
    {
      float acc = wsf[BOUTF + t];
#pragma unroll
      for (int j = 0; j < 8; ++j) acc = fmaf(sx[j], wsf[WOUTF + t * 8 + j], acc);
      out[obase + t] = acc;               // a = 0..15
    }
    if (t < 4) {
      const int a = 16 + t;
      float acc = wsf[BOUTF + a];
#pragma unroll
      for (int j = 0; j < 8; ++j) acc = fmaf(sx[j], wsf[WOUTF + a * 8 + j], acc);
      out[obase + a] = acc;               // a = 16..19
    }
  }
}

extern "C" void kernel_launch(void* const* d_in, const int* in_sizes, int n_in,
                              void* d_out, int out_size, void* d_ws, size_t ws_size,
                              hipStream_t stream) {
  const int*   dice_type  = (const int*)d_in[0];
  const int*   dice_star  = (const int*)d_in[1];
  const int*   summon_lvl = (const int*)d_in[2];
  const float* emb_dice   = (const float*)d_in[3];
  const float* emb_star   = (const float*)d_in[4];
  const float* emb_btns   = (const float*)d_in[5];
  const float* Wout       = (const float*)d_in[6];
  const float* bout       = (const float*)d_in[7];
  const float* Wqkv0      = (const float*)d_in[8];
  const float* bqkv0      = (const float*)d_in[9];
  const float* Wo0        = (const float*)d_in[10];
  const float* bo0        = (const float*)d_in[11];
  const float* Wl0        = (const float*)d_in[12];
  const float* bl0        = (const float*)d_in[13];
  const float* Wqkv1      = (const float*)d_in[14];
  const float* bqkv1      = (const float*)d_in[15];
  const float* Wo1        = (const float*)d_in[16];
  const float* bo1        = (const float*)d_in[17];
  const float* Wl1        = (const float*)d_in[18];
  const float* bl1        = (const float*)d_in[19];
  float* out = (float*)d_out;
  h2* ws = (h2*)d_ws;

  hipLaunchKernelGGL(BetterBot_setup, dim3(1), dim3(256), 0, stream,
                     emb_dice, emb_star, emb_btns, Wout, bout,
                     Wqkv0, bqkv0, Wqkv1, bqkv1,
                     Wo0, bo0, Wl0, bl0, Wo1, bo1, Wl1, bl1, ws);
  hipLaunchKernelGGL(BetterBot_44169443672375_kernel, dim3(BTOT / (EPB * ITERS)), dim3(256),
                     0, stream, dice_type, dice_star, summon_lvl, (const h2*)ws, out);
}

// Round 13
// 122.323 us; speedup vs baseline: 1.0101x; 1.0101x over previous
//
#include <hip/hip_runtime.h>
#include <math.h>

// B=65536, D=8, H=2 (hd=4), S=15 tokens, A=20 outputs.
// R13 = R10 verbatim (best measured, 120.7us). Structure: one-block setup
// kernel packs all weights (pk-f16, column/row reorders, C_SCALE and 1/15
// folded) and precomputes the block-invariant layer-0 tables (x, v, 32x33 exp)
// into d_ws; main kernel (4096 blocks x 256) copies the 5.2KB table to LDS,
// runs table-driven layer 0 (pk-f16, f32 sums), layer-1 qkv (pk-f16 q/k, f32
// fdot2 v), layer-1 attention (f16 fdot2 scores, f32 exp/sum/PV), pk-f16
// epilogue matmuls, h2 butterfly mean, coalesced f32 out.
// R11 (no 2nd barrier) and R12 (persistent x2) both measured neutral/regress.
#define EPB 16
#define BTOT 65536
#define C_SCALE 0.72134752044f  // 0.5 * log2(e)

typedef _Float16 h2 __attribute__((ext_vector_type(2)));
typedef __fp16 fp16v2 __attribute__((ext_vector_type(2)));

// d_ws h2 layout offsets (h2 = 4B, same index granularity as float)
#define WQKV1 0     // 96: [c2=0..11][j pairs]; q rows (2c,2c+1)*C_SCALE, k rows seq
#define BQKV1 96    // 12
#define WO0   108   // 32: cols reordered (p, p+4) for interleaved-o input
#define BO0   140   // 4
#define WL0   144   // 32: natural
#define BL0   176   // 4
#define WO1   180   // 32: cols reordered
#define BO1   212   // 4
#define WL1   216   // 32: natural
#define BL1   248   // 4
#define WV1P  256   // 32: [r=0..7][p=0..3]; rows permuted v0,v4,v1,v5,v2,v6,v3,v7
#define BV1F  288   // 8 f32 biases (permuted)
#define XT    304   // 128: x rows, seq pairs
#define VT    432   // 128: layer-0 v rows, head-interleaved pairs (stride 4)
#define ET    560   // 1056: e[qi*33+ki] = (e_h0, e_h1) f16
#define WOUTF 1616  // 160 f32: Wout/15, [a][j]
#define BOUTF 1776  // 20 f32: bout
#define TBL0  304
#define TBLV4 328
#define XTO 0
#define VTO 128
#define ETO 256

__device__ __forceinline__ float exp2_fast(float x) { return __builtin_amdgcn_exp2f(x); }
__device__ __forceinline__ float rcp_fast(float x)  { return __builtin_amdgcn_rcpf(x); }
__device__ __forceinline__ h2 pkrtz(float a, float b) {
  fp16v2 r = __builtin_amdgcn_cvt_pkrtz(a, b);
  return __builtin_bit_cast(h2, r);
}
__device__ __forceinline__ float fdot2f(h2 a, h2 b, float c) {
#if defined(__has_builtin) && __has_builtin(__builtin_amdgcn_fdot2)
  return __builtin_amdgcn_fdot2(a, b, c, false);
#else
  return (float)a.x * (float)b.x + (float)a.y * (float)b.y + c;
#endif
}

union F4H2 { float4 f; h2 h[4]; };
union H2I { h2 h; int i; };

__device__ __forceinline__ void mm8_h2(const h2* __restrict__ wp, int woff, int boff,
                                       const h2 in2[4], h2 out2[4])
{
#pragma unroll
  for (int c2 = 0; c2 < 4; ++c2) {
    h2 acc = wp[boff + c2];
#pragma unroll
    for (int p = 0; p < 4; ++p) {
      acc += (h2)(in2[p].x) * wp[woff + c2 * 8 + 2 * p];
      acc += (h2)(in2[p].y) * wp[woff + c2 * 8 + 2 * p + 1];
    }
    out2[c2] = acc;
  }
}

__global__ void BetterBot_setup(
    const float* __restrict__ emb_dice, const float* __restrict__ emb_star,
    const float* __restrict__ emb_btns,
    const float* __restrict__ Wout, const float* __restrict__ bout,
    const float* __restrict__ Wqkv0, const float* __restrict__ bqkv0,
    const float* __restrict__ Wqkv1, const float* __restrict__ bqkv1,
    const float* __restrict__ Wo0, const float* __restrict__ bo0,
    const float* __restrict__ Wl0, const float* __restrict__ bl0,
    const float* __restrict__ Wo1, const float* __restrict__ bo1,
    const float* __restrict__ Wl1, const float* __restrict__ bl1,
    h2* __restrict__ ws)
{
  __shared__ float qs[32][8], ks[32][8], vs[32][8];
  const int tid = threadIdx.x;
  float* wsf = (float*)ws;

  if (tid < 96) {
    const int c2 = tid >> 3, j = tid & 7;
    int ra, rb; float s = 1.0f;
    if (c2 < 4)      { ra = 2 * c2; rb = ra + 1; s = C_SCALE; }
    else if (c2 < 8) { ra = 8 + 2 * (c2 - 4); rb = ra + 1; }
    else             { ra = 16 + (c2 - 8); rb = ra + 4; }
    ws[tid] = pkrtz(Wqkv1[ra * 8 + j] * s, Wqkv1[rb * 8 + j] * s);
  } else if (tid < 108) {
    const int c2 = tid - 96;
    int ra, rb; float s = 1.0f;
    if (c2 < 4)      { ra = 2 * c2; rb = ra + 1; s = C_SCALE; }
    else if (c2 < 8) { ra = 8 + 2 * (c2 - 4); rb = ra + 1; }
    else             { ra = 16 + (c2 - 8); rb = ra + 4; }
    ws[tid] = pkrtz(bqkv1[ra] * s, bqkv1[rb] * s);
  } else if (tid < 140) {
    const int k = tid - 108, c2 = k >> 3, j = k & 7, p = j >> 1;
    const int col = (j & 1) ? (p + 4) : p;
    ws[tid] = pkrtz(Wo0[(2 * c2) * 8 + col], Wo0[(2 * c2 + 1) * 8 + col]);
  } else if (tid < 144) {
    const int c2 = tid - 140;
    ws[tid] = pkrtz(bo0[2 * c2], bo0[2 * c2 + 1]);
  } else if (tid < 176) {
    const int k = tid - 144, c2 = k >> 3, j = k & 7;
    ws[tid] = pkrtz(Wl0[(2 * c2) * 8 + j], Wl0[(2 * c2 + 1) * 8 + j]);
  } else if (tid < 180) {
    const int c2 = tid - 176;
    ws[tid] = pkrtz(bl0[2 * c2], bl0[2 * c2 + 1]);
  } else if (tid < 212) {
    const int k = tid - 180, c2 = k >> 3, j = k & 7, p = j >> 1;
    const int col = (j & 1) ? (p + 4) : p;
    ws[tid] = pkrtz(Wo1[(2 * c2) * 8 + col], Wo1[(2 * c2 + 1) * 8 + col]);
  } else if (tid < 216) {
    const int c2 = tid - 212;
    ws[tid] = pkrtz(bo1[2 * c2], bo1[2 * c2 + 1]);
  } else if (tid < 248) {
    const int k = tid - 216, c2 = k >> 3, j = k & 7;
    ws[tid] = pkrtz(Wl1[(2 * c2) * 8 + j], Wl1[(2 * c2 + 1) * 8 + j]);
  } else if (tid < 252) {
    const int c2 = tid - 248;
    ws[tid] = pkrtz(bl1[2 * c2], bl1[2 * c2 + 1]);
  }
  if (tid < 32) {
    const int r = tid >> 2, p = tid & 3;
    const int row = 16 + (r >> 1) + (r & 1) * 4;   // perm: v0,v4,v1,v5,v2,v6,v3,v7
    ws[WV1P + tid] = pkrtz(Wqkv1[row * 8 + 2 * p], Wqkv1[row * 8 + 2 * p + 1]);
  } else if (tid < 40) {
    const int r = tid - 32;
    const int row = 16 + (r >> 1) + (r & 1) * 4;
    wsf[BV1F + r] = bqkv1[row];
  }
  if (tid < 160)      wsf[WOUTF + tid] = Wout[tid] * (1.0f / 15.0f);
  else if (tid < 180) wsf[BOUTF + tid - 160] = bout[tid - 160];

  {
    const int c = tid >> 3, l8 = tid & 7;
    const float* er;
    if (c < 15)      er = emb_dice + 8 * c;
    else if (c < 30) er = emb_star + 8 * (c - 15);
    else             er = emb_btns + 8 * (c - 30);
    const float4 r0 = ((const float4*)er)[0];
    const float4 r1 = ((const float4*)er)[1];
    float r[8] = {r0.x, r0.y, r0.z, r0.w, r1.x, r1.y, r1.z, r1.w};
    if (l8 < 4) ws[XT + c * 4 + l8] = pkrtz(r[2 * l8], r[2 * l8 + 1]);
    float aq = bqkv0[l8], ak = bqkv0[8 + l8], av = bqkv0[16 + l8];
#pragma unroll
    for (int j = 0; j < 8; ++j) {
      aq = fmaf(r[j], Wqkv0[l8 * 8 + j], aq);
      ak = fmaf(r[j], Wqkv0[(8 + l8) * 8 + j], ak);
      av = fmaf(r[j], Wqkv0[(16 + l8) * 8 + j], av);
    }
    qs[c][l8] = aq * C_SCALE;
    ks[c][l8] = ak;
    vs[c][l8] = av;
  }
  __syncthreads();

  {
    const int qi = tid >> 3, l8 = tid & 7;
    float q[8];
#pragma unroll
    for (int j = 0; j < 8; ++j) q[j] = qs[qi][j];
#pragma unroll
    for (int jj = 0; jj < 4; ++jj) {
      const int ki = l8 + 8 * jj;
      float s0 = q[0] * ks[ki][0];
      s0 = fmaf(q[1], ks[ki][1], s0); s0 = fmaf(q[2], ks[ki][2], s0); s0 = fmaf(q[3], ks[ki][3], s0);
      float s1 = q[4] * ks[ki][4];
      s1 = fmaf(q[5], ks[ki][5], s1); s1 = fmaf(q[6], ks[ki][6], s1); s1 = fmaf(q[7], ks[ki][7], s1);
      ws[ET + qi * 33 + ki] = pkrtz(exp2_fast(s0), exp2_fast(s1));
    }
  }
  if (tid < 32) {
#pragma unroll
    for (int p = 0; p < 4; ++p) ws[VT + tid * 4 + p] = pkrtz(vs[tid][p], vs[tid][p + 4]);
  }
}

__global__ __launch_bounds__(256, 8) void BetterBot_44169443672375_kernel(
    const int* __restrict__ dice_type, const int* __restrict__ dice_star,
    const int* __restrict__ summon_lvl,
    const h2* __restrict__ wp,
    float* __restrict__ out)
{
  __shared__ __align__(16) h2 tbl[1312];        // [xT 128 | vT 128 | eT 1056]
  __shared__ __align__(16) h2 kvb[EPB][17][8];  // token: [k 4xh2 | v 4xh2]; stride 17*32B

  const int tid = threadIdx.x;
  const int e = tid >> 4;       // element in block
  const int t = tid & 15;       // token (15 = pad lane)
  const int ge = blockIdx.x * EPB + e;
  const float* wsf = (const float*)wp;

  // ---- phase 1: global->LDS table copy + packed indices via shfl ----
  {
    float4* d = (float4*)tbl;
    const float4* s = (const float4*)(wp + TBL0);
    d[tid] = s[tid];
    if (tid < TBLV4 - 256) d[256 + tid] = s[256 + tid];
  }
  int myc = 0;
  if (t < 15) {
    if (t < 5)       myc = dice_type[ge * 5 + t];
    else if (t < 10) myc = 15 + dice_star[ge * 5 + (t - 5)];
    else             myc = 30 + summon_lvl[ge * 5 + (t - 10)];
  }
  // pack the group's 16 token indices into 4 byte-packed words (all lanes active)
  int W[4];
  {
    int wv = myc << (8 * (t & 3));
    wv |= __shfl_xor(wv, 1);
    wv |= __shfl_xor(wv, 2);
    const int gb = (tid & 63) & 48;   // group base within wave
#pragma unroll
    for (int k = 0; k < 4; ++k) W[k] = __shfl(wv, gb + 4 * k);
  }
  __syncthreads();

  // ---- layer 0 (table-driven pk) + layer-1 qkv ----
  h2 x2[4] = {(h2)(_Float16)0.f, (h2)(_Float16)0.f, (h2)(_Float16)0.f, (h2)(_Float16)0.f};
  h2 q2[4];
  if (t < 15) {
    F4H2 xx; xx.f = *(const float4*)(&tbl[XTO + myc * 4]);
#pragma unroll
    for (int p = 0; p < 4; ++p) x2[p] = xx.h[p];

    h2 o2[4] = {(h2)(_Float16)0.f, (h2)(_Float16)0.f, (h2)(_Float16)0.f, (h2)(_Float16)0.f};
    h2 os2 = (h2)(_Float16)0.f;          // pk sums; table e bounded (R9-proven)
    const h2* myE = tbl + ETO + myc * 33;
#pragma unroll
    for (int u = 0; u < 15; ++u) {
      const int uc = (W[u >> 2] >> (8 * (u & 3))) & 0xff;
      const h2 ee2 = myE[uc];
      F4H2 vv; vv.f = *(const float4*)(&tbl[VTO + uc * 4]);
      os2 += ee2;
      o2[0] += ee2 * vv.h[0];
      o2[1] += ee2 * vv.h[1];
      o2[2] += ee2 * vv.h[2];
      o2[3] += ee2 * vv.h[3];
    }
    const h2 rp2 = pkrtz(rcp_fast((float)os2.x), rcp_fast((float)os2.y));
#pragma unroll
    for (int p = 0; p < 4; ++p) o2[p] *= rp2;

    h2 y2[4], xn2[4], hh2[4];
    mm8_h2(wp, WO0, BO0, o2, y2);
#pragma unroll
    for (int p = 0; p < 4; ++p) xn2[p] = x2[p] + y2[p];
    mm8_h2(wp, WL0, BL0, xn2, hh2);
    const h2 z2 = (h2)(_Float16)0.f;
#pragma unroll
    for (int p = 0; p < 4; ++p) x2[p] = xn2[p] + __builtin_elementwise_max(hh2[p], z2);

    // layer-1 q,k (pk-f16) + v (f32 fdot2, permuted rows)
    h2 qkv2[8];
#pragma unroll
    for (int c2 = 0; c2 < 8; ++c2) {
      h2 acc = wp[BQKV1 + c2];
#pragma unroll
      for (int p = 0; p < 4; ++p) {
        acc += (h2)(x2[p].x) * wp[WQKV1 + c2 * 8 + 2 * p];
        acc += (h2)(x2[p].y) * wp[WQKV1 + c2 * 8 + 2 * p + 1];
      }
      qkv2[c2] = acc;
    }
#pragma unroll
    for (int p = 0; p < 4; ++p) q2[p] = qkv2[p];
    float vv[8];
#pragma unroll
    for (int r = 0; r < 8; ++r) {
      float acc = wsf[BV1F + r];
#pragma unroll
      for (int p = 0; p < 4; ++p) acc = fdot2f(x2[p], wp[WV1P + r * 4 + p], acc);
      vv[r] = acc;
    }
    F4H2 kw;
#pragma unroll
    for (int p = 0; p < 4; ++p) kw.h[p] = qkv2[4 + p];
    *(float4*)(&kvb[e][t][0]) = kw.f;
    F4H2 vw;                              // v as f16 pairs (bounded; e stays f32)
    vw.h[0] = pkrtz(vv[0], vv[1]);
    vw.h[1] = pkrtz(vv[2], vv[3]);
    vw.h[2] = pkrtz(vv[4], vv[5]);
    vw.h[3] = pkrtz(vv[6], vv[7]);
    *(float4*)(&kvb[e][t][4]) = vw.f;
  }
  __syncthreads();

  // ---- layer 1: fdot2 f16 scores, f32 exp/sums/PV (fma_mix on f16 v) ----
  if (t < 15) {
    float o[8] = {0.f, 0.f, 0.f, 0.f, 0.f, 0.f, 0.f, 0.f};  // permuted order
    float sum0 = 0.f, sum1 = 0.f;
#pragma unroll
    for (int u = 0; u < 15; ++u) {
      F4H2 kk; kk.f = *(const float4*)(&kvb[e][u][0]);
      F4H2 vh; vh.f = *(const float4*)(&kvb[e][u][4]);
      const float s0 = fdot2f(q2[0], kk.h[0], fdot2f(q2[1], kk.h[1], 0.f));
      const float s1 = fdot2f(q2[2], kk.h[2], fdot2f(q2[3], kk.h[3], 0.f));
      const float e0 = exp2_fast(s0);
      const float e1 = exp2_fast(s1);
      sum0 += e0; sum1 += e1;
      o[0] = fmaf(e0, (float)vh.h[0].x, o[0]);
      o[1] = fmaf(e1, (float)vh.h[0].y, o[1]);
      o[2] = fmaf(e0, (float)vh.h[1].x, o[2]);
      o[3] = fmaf(e1, (float)vh.h[1].y, o[3]);
      o[4] = fmaf(e0, (float)vh.h[2].x, o[4]);
      o[5] = fmaf(e1, (float)vh.h[2].y, o[5]);
      o[6] = fmaf(e0, (float)vh.h[3].x, o[6]);
      o[7] = fmaf(e1, (float)vh.h[3].y, o[7]);
    }
    const float r0 = rcp_fast(sum0), r1 = rcp_fast(sum1);
    h2 po2[4];
#pragma unroll
    for (int i = 0; i < 4; ++i) po2[i] = pkrtz(o[2 * i] * r0, o[2 * i + 1] * r1);

    h2 y2[4], xn2[4], hh2[4];
    mm8_h2(wp, WO1, BO1, po2, y2);
#pragma unroll
    for (int p = 0; p < 4; ++p) xn2[p] = x2[p] + y2[p];
    mm8_h2(wp, WL1, BL1, xn2, hh2);
    const h2 z2 = (h2)(_Float16)0.f;
#pragma unroll
    for (int p = 0; p < 4; ++p) x2[p] = xn2[p] + __builtin_elementwise_max(hh2[p], z2);
  } else {
#pragma unroll
    for (int p = 0; p < 4; ++p) x2[p] = (h2)(_Float16)0.f;  // pad lane contributes 0
  }

  // ---- epilogue: token-sum via h2 butterfly; 1/15 pre-folded into Wout' ----
  h2 p2[4];
#pragma unroll
  for (int p = 0; p < 4; ++p) p2[p] = x2[p];
#pragma unroll
  for (int m = 1; m <= 8; m <<= 1) {
#pragma unroll
    for (int p = 0; p < 4; ++p) {
      H2I a; a.h = p2[p];
      H2I b; b.i = __shfl_xor(a.i, m);
      p2[p] += b.h;
    }
  }
  float sx[8];
#pragma unroll
  for (int i = 0; i < 4; ++i) { sx[2 * i] = (float)p2[i].x; sx[2 * i + 1] = (float)p2[i].y; }

  const int obase = ge * 20;
  {
    float acc = wsf[BOUTF + t];
#pragma unroll
    for (int j = 0; j < 8; ++j) acc = fmaf(sx[j], wsf[WOUTF + t * 8 + j], acc);
    out[obase + t] = acc;               // a = 0..15
  }
  if (t < 4) {
    const int a = 16 + t;
    float acc = wsf[BOUTF + a];
#pragma unroll
    for (int j = 0; j < 8; ++j) acc = fmaf(sx[j], wsf[WOUTF + a * 8 + j], acc);
    out[obase + a] = acc;               // a = 16..19
  }
}

extern "C" void kernel_launch(void* const* d_in, const int* in_sizes, int n_in,
                              void* d_out, int out_size, void* d_ws, size_t ws_size,
                              hipStream_t stream) {
  const int*   dice_type  = (const int*)d_in[0];
  const int*   dice_star  = (const int*)d_in[1];
  const int*   summon_lvl = (const int*)d_in[2];
  const float* emb_dice   = (const float*)d_in[3];
  const float* emb_star   = (const float*)d_in[4];
  const float* emb_btns   = (const float*)d_in[5];
  const float* Wout       = (const float*)d_in[6];
  const float* bout       = (const float*)d_in[7];
  const float* Wqkv0      = (const float*)d_in[8];
  const float* bqkv0      = (const float*)d_in[9];
  const float* Wo0        = (const float*)d_in[10];
  const float* bo0        = (const float*)d_in[11];
  const float* Wl0        = (const float*)d_in[12];
  const float* bl0        = (const float*)d_in[13];
  const float* Wqkv1      = (const float*)d_in[14];
  const float* bqkv1      = (const float*)d_in[15];
  const float* Wo1        = (const float*)d_in[16];
  const float* bo1        = (const float*)d_in[17];
  const float* Wl1        = (const float*)d_in[18];
  const float* bl1        = (const float*)d_in[19];
  float* out = (float*)d_out;
  h2* ws = (h2*)d_ws;

  hipLaunchKernelGGL(BetterBot_setup, dim3(1), dim3(256), 0, stream,
                     emb_dice, emb_star, emb_btns, Wout, bout,
                     Wqkv0, bqkv0, Wqkv1, bqkv1,
                     Wo0, bo0, Wl0, bl0, Wo1, bo1, Wl1, bl1, ws);
  hipLaunchKernelGGL(BetterBot_44169443672375_kernel, dim3(BTOT / EPB), dim3(256), 0, stream,
                     dice_type, dice_star, summon_lvl, (const h2*)ws, out);
}